// Round 8
// baseline (220.626 us; speedup 1.0000x reference)
//
#include <hip/hip_runtime.h>
#include <math.h>

// TopKRouter: x[16384,2048] fp32, W[64,2048] fp32
// out: [0..32767] top2 indices (as float), [32768..65535] gates, [65536] aux
// Split-fp16 MFMA (3-term). Wave-level K-split: each wave owns a disjoint
// 512-k slice x all 64 experts -> wave-private LDS staging (in-order DS pipe,
// ZERO barriers in K-loop), 12 MFMA per 2 ds_read_b128. Partial logits
// reduced across waves once at the end.
#define NTOK 16384
#define DDIM 2048
#define NEXP 64
#define TM   16                 // tokens per block (1 MFMA M-tile)
#define NBLK (NTOK / TM)        // 1024 blocks -> 4 blocks/CU
#define KPW  512                // k per wave
#define NCHW 8                  // chunks of 64 k per wave

typedef _Float16 half4v __attribute__((ext_vector_type(4)));
typedef _Float16 half8v __attribute__((ext_vector_type(8)));
typedef float    f32x4  __attribute__((ext_vector_type(4)));

#define MFMA16(a, b, c) __builtin_amdgcn_mfma_f32_16x16x32_f16((a), (b), (c), 0, 0, 0)

// W prep: fp32 -> (wh, wl) fp16 in MFMA-B fragment-linear layout (r5-verified):
// element (e,k): S=k>>5, nb=e>>4, nl=e&15, q=(k>>3)&3, j=k&7
// off = S*2048 + nb*512 + q*128 + nl*8 + j
__global__ __launch_bounds__(256) void prep_kernel(const float* __restrict__ W,
                                                   _Float16* __restrict__ Wh,
                                                   _Float16* __restrict__ Wl,
                                                   float* __restrict__ accg) {
    int idx = blockIdx.x * 256 + threadIdx.x;       // 512 blocks -> 131072
    int e = idx >> 11, k = idx & 2047;
    float w = W[idx];
    _Float16 h = (_Float16)w;
    _Float16 l = (_Float16)(w - (float)h);
    int S = k >> 5, nb = e >> 4, nl = e & 15, q = (k >> 3) & 3, j = k & 7;
    size_t off = (size_t)S * 2048 + nb * 512 + q * 128 + nl * 8 + j;
    Wh[off] = h;
    Wl[off] = l;
    if (blockIdx.x == 0 && threadIdx.x < 128) accg[threadIdx.x] = 0.0f;
}

__device__ inline void cvt_store(_Float16* __restrict__ Hp, _Float16* __restrict__ Lp,
                                 int off, float4 v) {
    half4v h, l;
    h.x = (_Float16)v.x; l.x = (_Float16)(v.x - (float)h.x);
    h.y = (_Float16)v.y; l.y = (_Float16)(v.y - (float)h.y);
    h.z = (_Float16)v.z; l.z = (_Float16)(v.z - (float)h.z);
    h.w = (_Float16)v.w; l.w = (_Float16)(v.w - (float)h.w);
    *(half4v*)&Hp[off] = h;
    *(half4v*)&Lp[off] = l;
}

__global__ __launch_bounds__(256, 4) void router_kernel(
    const float* __restrict__ x, const _Float16* __restrict__ Wh,
    const _Float16* __restrict__ Wl, float* __restrict__ accg,
    float* __restrict__ out)
{
    // wave-private A staging: 1 chunk = 2 K32-steps x 64 lanes x 8 halfs
    __shared__ __align__(16) _Float16 Ah[4][1024];   // 8 KB
    __shared__ __align__(16) _Float16 Al[4][1024];   // 8 KB
    __shared__ float red[4][TM][NEXP + 1];           // 16.6 KB partial logits
    __shared__ float cnt[NEXP];

    const int tid  = threadIdx.x;
    const int lane = tid & 63;
    const int wv   = __builtin_amdgcn_readfirstlane(tid >> 6);  // k-slice 0..3
    const int m0   = blockIdx.x * TM;

    if (tid < NEXP) cnt[tid] = 0.0f;

    _Float16* ah_buf = Ah[wv];
    _Float16* al_buf = Al[wv];

    // staging map: load i (i=0..3): tok = i*4 + (lane>>4), kk = (lane&15)*4
    const int tokb = lane >> 4;            // 0..3
    const int kk   = (lane & 15) * 4;      // 0..60
    const int S0   = kk >> 5, q0 = (kk >> 3) & 3, j0 = kk & 7;
    const int offA = (S0 * 64 + q0 * 16 + tokb) * 8 + j0;  // + 32*i per load

    const int kb = wv * KPW;
    const float* gx = x + (size_t)(m0 + tokb) * DDIM + kb + kk;  // + i*4 rows

    // W-frag base (frag-linear, L2-hot); step Sg -> + Sg*2048, block nb -> + nb*512
    const _Float16* whp = Wh + lane * 8;
    const _Float16* wlp = Wl + lane * 8;

    f32x4 acc[4];
    #pragma unroll
    for (int nb = 0; nb < 4; ++nb) acc[nb] = (f32x4){0.f, 0.f, 0.f, 0.f};

    // 2-chunk-deep x prefetch
    float4 stg[2][4];
    #pragma unroll
    for (int c = 0; c < 2; ++c)
        #pragma unroll
        for (int i = 0; i < 4; ++i)
            stg[c][i] = *(const float4*)(gx + (size_t)(4 * i) * DDIM + c * 64);

    for (int c = 0; c < NCHW; ++c) {
        const int p = c & 1;
        // stage chunk c -> wave-private LDS (in-order pipe: no barrier;
        // these writes issue after the prior chunk's reads in program order)
        #pragma unroll
        for (int i = 0; i < 4; ++i)
            cvt_store(ah_buf, al_buf, offA + 32 * i, stg[p][i]);
        // prefetch chunk c+2 (wrap reload harmless)
        const int cf = (c + 2 < NCHW) ? c + 2 : 0;
        #pragma unroll
        for (int i = 0; i < 4; ++i)
            stg[p][i] = *(const float4*)(gx + (size_t)(4 * i) * DDIM + cf * 64);
        #pragma unroll
        for (int s = 0; s < 2; ++s) {
            const int Sg = wv * 16 + c * 2 + s;      // global K32 step
            const _Float16* wh_s = whp + (size_t)Sg * 2048;
            const _Float16* wl_s = wlp + (size_t)Sg * 2048;
            half8v bh[4], bl[4];
            #pragma unroll
            for (int nb = 0; nb < 4; ++nb) {
                bh[nb] = *(const half8v*)(wh_s + nb * 512);
                bl[nb] = *(const half8v*)(wl_s + nb * 512);
            }
            half8v ah = *(const half8v*)&ah_buf[(s * 64 + lane) * 8];
            half8v al = *(const half8v*)&al_buf[(s * 64 + lane) * 8];
            #pragma unroll
            for (int nb = 0; nb < 4; ++nb) {
                acc[nb] = MFMA16(al, bh[nb], acc[nb]);
                acc[nb] = MFMA16(ah, bl[nb], acc[nb]);
                acc[nb] = MFMA16(ah, bh[nb], acc[nb]);
            }
        }
    }

    // ---- partial logits -> LDS; C layout: row m=(lane>>4)*4+r, col n=lane&15 ----
    {
        const int q  = lane >> 4;
        const int nl = lane & 15;
        #pragma unroll
        for (int nb = 0; nb < 4; ++nb)
            #pragma unroll
            for (int r = 0; r < 4; ++r)
                red[wv][q * 4 + r][nb * 16 + nl] = acc[nb][r];
    }
    __syncthreads();

    // ---- softmax + top-2: 8 threads per token (16 tok x 8 = 128 thr) ----
    if (tid < 128) {
        const int m = tid >> 3;
        const int j = tid & 7;
        float l[8];
        #pragma unroll
        for (int i = 0; i < 8; ++i)
            l[i] = (red[0][m][j * 8 + i] + red[1][m][j * 8 + i]) +
                   (red[2][m][j * 8 + i] + red[3][m][j * 8 + i]);

        float mx = l[0];
        #pragma unroll
        for (int i = 1; i < 8; ++i) mx = fmaxf(mx, l[i]);
        #pragma unroll
        for (int off = 1; off < 8; off <<= 1) mx = fmaxf(mx, __shfl_xor(mx, off, 8));

        float ev[8];
        float zs = 0.f;
        float v1 = -INFINITY, v2 = -INFINITY;
        int i1 = 0, i2 = 0;
        #pragma unroll
        for (int i = 0; i < 8; ++i) {
            ev[i] = __expf(l[i] - mx);
            zs += ev[i];
            int e = j * 8 + i;
            if (l[i] > v1)      { v2 = v1; i2 = i1; v1 = l[i]; i1 = e; }
            else if (l[i] > v2) { v2 = l[i]; i2 = e; }
        }
        #pragma unroll
        for (int off = 1; off < 8; off <<= 1) zs += __shfl_xor(zs, off, 8);

        // merge top-2 across 8 lanes (value desc, index asc on ties = lax.top_k)
        #pragma unroll
        for (int off = 1; off < 8; off <<= 1) {
            float ov1 = __shfl_xor(v1, off, 8);
            int   oi1 = __shfl_xor(i1, off, 8);
            float ov2 = __shfl_xor(v2, off, 8);
            int   oi2 = __shfl_xor(i2, off, 8);
            bool afirst = (v1 > ov1) || (v1 == ov1 && i1 < oi1);
            if (afirst) {
                bool t = (v2 > ov1) || (v2 == ov1 && i2 < oi1);
                v2 = t ? v2 : ov1;
                i2 = t ? i2 : oi1;
            } else {
                bool t = (ov2 > v1) || (ov2 == v1 && oi2 < i1);
                v2 = t ? ov2 : v1;
                i2 = t ? oi2 : i1;
                v1 = ov1;
                i1 = oi1;
            }
        }

        const float invz = 1.0f / zs;
        if (j == 0) {
            float p1 = invz;                      // v1 == mx exactly
            float p2 = __expf(v2 - mx) * invz;
            float sden = p1 + p2 + 1e-9f;
            int tok = m0 + m;
            out[tok * 2 + 0] = (float)i1;
            out[tok * 2 + 1] = (float)i2;
            out[32768 + tok * 2 + 0] = p1 / sden;
            out[32768 + tok * 2 + 1] = p2 / sden;
            atomicAdd(&cnt[i1], 1.0f);
            atomicAdd(&cnt[i2], 1.0f);
        }

        // probs writeback into red[0] (own slots only)
        #pragma unroll
        for (int i = 0; i < 8; ++i) red[0][m][j * 8 + i] = ev[i] * invz;
    }
    __syncthreads();

    // global accumulators (accg zeroed by prep each launch)
    if (tid < NEXP) {
        atomicAdd(&accg[tid], cnt[tid]);
    } else if (tid < 128) {
        int e = tid - 64;
        float s = 0.f;
        #pragma unroll
        for (int t = 0; t < TM; ++t) s += red[0][t][e];
        atomicAdd(&accg[64 + e], s);
    }
}

__global__ void finalize_kernel(const float* __restrict__ accg,
                                float* __restrict__ out)
{
    int t = threadIdx.x;   // 64 threads
    float c = accg[t];
    float p = accg[64 + t];
    float term = (c / (float)(NTOK * 2)) * (p / (float)NTOK);
    #pragma unroll
    for (int off = 1; off < 64; off <<= 1) term += __shfl_xor(term, off, 64);
    if (t == 0) out[65536] = 0.01f * (float)NEXP * term;
}

extern "C" void kernel_launch(void* const* d_in, const int* in_sizes, int n_in,
                              void* d_out, int out_size, void* d_ws, size_t ws_size,
                              hipStream_t stream) {
    const float* x = (const float*)d_in[0];   // [4,4096,2048]
    const float* W = (const float*)d_in[1];   // [64,2048]
    float* out  = (float*)d_out;              // 65537 floats
    float* accg = (float*)d_ws;               // 128 floats
    _Float16* Wh = (_Float16*)(accg + 128);   // 131072 halfs (256 KB)
    _Float16* Wl = Wh + (size_t)DDIM * NEXP;  // 131072 halfs (256 KB)

    prep_kernel<<<512, 256, 0, stream>>>(W, Wh, Wl, accg);
    router_kernel<<<NBLK, 256, 0, stream>>>(x, Wh, Wl, accg, out);
    finalize_kernel<<<1, 64, 0, stream>>>(accg, out);
}